// Round 1
// baseline (860.863 us; speedup 1.0000x reference)
//
#include <hip/hip_runtime.h>
#include <hip/hip_bf16.h>

#define NFEAT 128

typedef __attribute__((ext_vector_type(8))) short frag8;
typedef __attribute__((ext_vector_type(4))) float f32x4;

__device__ __forceinline__ unsigned short f2bf(float f) {
  unsigned int u = __builtin_bit_cast(unsigned int, f);
  u += 0x7fffu + ((u >> 16) & 1u);
  return (unsigned short)(u >> 16);
}
__device__ __forceinline__ float bf2f(unsigned short s) {
  return __builtin_bit_cast(float, ((unsigned int)s) << 16);
}

// ---------------- CSR build ----------------
__global__ void k_count(const int* __restrict__ dst, int* __restrict__ cnt, int E) {
  int i = blockIdx.x * blockDim.x + threadIdx.x;
  if (i < E) atomicAdd(&cnt[dst[i]], 1);
}

__global__ void k_scan1(const int* __restrict__ cnt, int* __restrict__ partial, int n) {
  __shared__ int sm[256];
  int t = threadIdx.x, i = blockIdx.x * 256 + t;
  sm[t] = (i < n) ? cnt[i] : 0;
  __syncthreads();
  for (int off = 128; off > 0; off >>= 1) {
    if (t < off) sm[t] += sm[t + off];
    __syncthreads();
  }
  if (t == 0) partial[blockIdx.x] = sm[0];
}

__global__ void k_scan2(const int* __restrict__ partial, int* __restrict__ blockoff,
                        int nb, int* __restrict__ row_ptr, int n) {
  __shared__ int sm[512];
  int t = threadIdx.x;
  int v = (t < nb) ? partial[t] : 0;
  sm[t] = v;
  __syncthreads();
  for (int off = 1; off < 512; off <<= 1) {
    int add = (t >= off) ? sm[t - off] : 0;
    __syncthreads();
    sm[t] += add;
    __syncthreads();
  }
  if (t < nb) blockoff[t] = sm[t] - v;
  if (t == nb - 1) row_ptr[n] = sm[t];
}

__global__ void k_scan3(const int* __restrict__ cnt, const int* __restrict__ blockoff,
                        int* __restrict__ row_ptr, int* __restrict__ cursor,
                        float* __restrict__ dinv, int n) {
  __shared__ int sm[256];
  int t = threadIdx.x, i = blockIdx.x * 256 + t;
  int v = (i < n) ? cnt[i] : 0;
  sm[t] = v;
  __syncthreads();
  for (int off = 1; off < 256; off <<= 1) {
    int add = (t >= off) ? sm[t - off] : 0;
    __syncthreads();
    sm[t] += add;
    __syncthreads();
  }
  if (i < n) {
    int rp = blockoff[blockIdx.x] + sm[t] - v;
    row_ptr[i] = rp;
    cursor[i] = rp;
    dinv[i] = (v > 0) ? (1.0f / (float)v) : 0.0f;
  }
}

__global__ void k_fill(const int* __restrict__ src, const int* __restrict__ dst,
                       int* __restrict__ cursor, int* __restrict__ csr, int E) {
  int i = blockIdx.x * blockDim.x + threadIdx.x;
  if (i < E) {
    int p = atomicAdd(&cursor[dst[i]], 1);
    csr[p] = src[i];
  }
}

// ---------------- weight fp32 -> bf16 ----------------
__global__ void k_cvtw(const float* __restrict__ w0, const float* __restrict__ w1,
                       const float* __restrict__ w2, const float* __restrict__ w3,
                       unsigned short* __restrict__ out) {
  int i = blockIdx.x * blockDim.x + threadIdx.x;  // 0..65535 (4 matrices of 128x128)
  int m = i >> 14, off = i & 16383;
  const float* src = (m == 0) ? w0 : (m == 1) ? w1 : (m == 2) ? w2 : w3;
  out[i] = f2bf(src[off]);
}

// ---------------- mean aggregation (gather over CSR) ----------------
// one wave per node; lane owns features 2*lane, 2*lane+1
template <bool IN_F32>
__global__ void k_aggregate(const void* __restrict__ Xin, const int* __restrict__ row_ptr,
                            const int* __restrict__ csr, const float* __restrict__ dinv,
                            unsigned int* __restrict__ Aout, int n) {
  int wv = threadIdx.x >> 6, lane = threadIdx.x & 63;
  int v = blockIdx.x * 4 + wv;
  if (v >= n) return;
  int beg = row_ptr[v], end = row_ptr[v + 1];
  float a0 = 0.f, a1 = 0.f;
  if constexpr (IN_F32) {
    const float* xp = (const float*)Xin;
    for (int j = beg; j < end; ++j) {
      int s = csr[j];
      float2 val = *(const float2*)(xp + (size_t)s * NFEAT + lane * 2);
      a0 += val.x;
      a1 += val.y;
    }
  } else {
    const unsigned int* xp = (const unsigned int*)Xin;
    for (int j = beg; j < end; ++j) {
      int s = csr[j];
      unsigned int u = xp[(size_t)s * (NFEAT / 2) + lane];
      a0 += bf2f((unsigned short)(u & 0xffffu));
      a1 += bf2f((unsigned short)(u >> 16));
    }
  }
  float dv = dinv[v];
  unsigned int packed = (unsigned int)f2bf(a0 * dv) | ((unsigned int)f2bf(a1 * dv) << 16);
  Aout[(size_t)v * (NFEAT / 2) + lane] = packed;
}

// ---------------- fused dual GEMM: Out = relu(A@Wl.T + bias + X@Wr.T) ----------------
// block = 256 threads = 4 waves; wave owns 16 rows x 128 cols; K = 128 (A) + 128 (X)
// MFMA 16x16x32 bf16. a-frag: lane -> row=(lane&15), k=(lane>>4)*8+j (contiguous 16B).
// b-frag from W (row n = output feature, row-major): lane -> col n=(lane&15)+16c, same k.
// C/D: col=lane&15, row=(lane>>4)*4+reg.
template <bool X_IS_F32>
__global__ __launch_bounds__(256) void k_gemm(
    const unsigned short* __restrict__ A,   // [M][128] bf16 (aggregated)
    const void* __restrict__ X,             // [M][128] f32 or bf16 (self features)
    const unsigned short* __restrict__ Wl,  // [128][128] bf16
    const unsigned short* __restrict__ Wr,  // [128][128] bf16
    const float* __restrict__ bias,         // [128]
    unsigned short* __restrict__ Out,       // [M][128] bf16 (relu applied)
    int M) {
  int wv = threadIdx.x >> 6, lane = threadIdx.x & 63;
  int m0 = blockIdx.x * 64 + wv * 16;
  int lr = lane & 15, kq = lane >> 4;
  int row = m0 + lr;
  bool rowok = row < M;
  int kb0 = kq * 8;
  f32x4 acc[8] = {};

  {  // A part (K=128)
    const unsigned short* ap = A + (size_t)(rowok ? row : 0) * NFEAT;
#pragma unroll
    for (int kk = 0; kk < 4; ++kk) {
      int kb = kk * 32 + kb0;
      frag8 a = {};
      if (rowok) a = *(const frag8*)(ap + kb);
#pragma unroll
      for (int c = 0; c < 8; ++c) {
        frag8 b = *(const frag8*)(Wl + (size_t)(c * 16 + lr) * NFEAT + kb);
        acc[c] = __builtin_amdgcn_mfma_f32_16x16x32_bf16(a, b, acc[c], 0, 0, 0);
      }
    }
  }
  {  // X part (K=128)
#pragma unroll
    for (int kk = 0; kk < 4; ++kk) {
      int kb = kk * 32 + kb0;
      frag8 a = {};
      if (rowok) {
        if constexpr (X_IS_F32) {
          const float* xp = (const float*)X + (size_t)row * NFEAT + kb;
          float4 v0 = *(const float4*)xp;
          float4 v1 = *(const float4*)(xp + 4);
          a[0] = (short)f2bf(v0.x); a[1] = (short)f2bf(v0.y);
          a[2] = (short)f2bf(v0.z); a[3] = (short)f2bf(v0.w);
          a[4] = (short)f2bf(v1.x); a[5] = (short)f2bf(v1.y);
          a[6] = (short)f2bf(v1.z); a[7] = (short)f2bf(v1.w);
        } else {
          a = *(const frag8*)((const unsigned short*)X + (size_t)row * NFEAT + kb);
        }
      }
#pragma unroll
      for (int c = 0; c < 8; ++c) {
        frag8 b = *(const frag8*)(Wr + (size_t)(c * 16 + lr) * NFEAT + kb);
        acc[c] = __builtin_amdgcn_mfma_f32_16x16x32_bf16(a, b, acc[c], 0, 0, 0);
      }
    }
  }
  // epilogue: bias + relu -> bf16  (writes only this wave's rows; in-place over X is safe)
#pragma unroll
  for (int c = 0; c < 8; ++c) {
#pragma unroll
    for (int r = 0; r < 4; ++r) {
      int orow = m0 + kq * 4 + r;
      if (orow < M) {
        int ocol = c * 16 + lr;
        float val = acc[c][r] + bias[ocol];
        val = fmaxf(val, 0.f);
        Out[(size_t)orow * NFEAT + ocol] = f2bf(val);
      }
    }
  }
}

// ---------------- layer 3 (N_CLS=7) + log_softmax ----------------
__global__ void k_layer3(const unsigned int* __restrict__ A,  // agg3, bf16 pairs
                         const unsigned int* __restrict__ H,  // h2, bf16 pairs
                         const float* __restrict__ W3l, const float* __restrict__ b3,
                         const float* __restrict__ W3r, float* __restrict__ out, int n) {
  int wv = threadIdx.x >> 6, lane = threadIdx.x & 63;
  int v = blockIdx.x * 4 + wv;
  if (v >= n) return;
  unsigned int ua = A[(size_t)v * (NFEAT / 2) + lane];
  unsigned int uh = H[(size_t)v * (NFEAT / 2) + lane];
  float a0 = bf2f((unsigned short)(ua & 0xffffu)), a1 = bf2f((unsigned short)(ua >> 16));
  float h0 = bf2f((unsigned short)(uh & 0xffffu)), h1 = bf2f((unsigned short)(uh >> 16));
  float s[7];
#pragma unroll
  for (int c = 0; c < 7; ++c) {
    float2 wl = *(const float2*)(W3l + c * NFEAT + lane * 2);
    float2 wr = *(const float2*)(W3r + c * NFEAT + lane * 2);
    s[c] = a0 * wl.x + a1 * wl.y + h0 * wr.x + h1 * wr.y;
  }
#pragma unroll
  for (int off = 32; off > 0; off >>= 1) {
#pragma unroll
    for (int c = 0; c < 7; ++c) s[c] += __shfl_xor(s[c], off);
  }
  float z[7], mx = -1e30f;
#pragma unroll
  for (int c = 0; c < 7; ++c) {
    z[c] = s[c] + b3[c];
    mx = fmaxf(mx, z[c]);
  }
  float se = 0.f;
#pragma unroll
  for (int c = 0; c < 7; ++c) se += __expf(z[c] - mx);
  float lse = mx + __logf(se);
  float val = z[0];
#pragma unroll
  for (int c = 1; c < 7; ++c) val = (lane == c) ? z[c] : val;
  if (lane < 7) out[(size_t)v * 7 + lane] = val - lse;
}

// ---------------- launch ----------------
extern "C" void kernel_launch(void* const* d_in, const int* in_sizes, int n_in,
                              void* d_out, int out_size, void* d_ws, size_t ws_size,
                              hipStream_t stream) {
  const float* x = (const float*)d_in[0];
  const int* ei = (const int*)d_in[1];
  const float* W1l = (const float*)d_in[2];
  const float* b1 = (const float*)d_in[3];
  const float* W1r = (const float*)d_in[4];
  const float* W2l = (const float*)d_in[5];
  const float* b2 = (const float*)d_in[6];
  const float* W2r = (const float*)d_in[7];
  const float* W3l = (const float*)d_in[8];
  const float* b3 = (const float*)d_in[9];
  const float* W3r = (const float*)d_in[10];
  float* out = (float*)d_out;

  int N = in_sizes[0] / NFEAT;
  int E = in_sizes[1] / 2;
  const int* src = ei;
  const int* dst = ei + E;

  char* ws = (char*)d_ws;
  size_t off = 0;
  auto alloc = [&](size_t bytes) {
    void* p = (void*)(ws + off);
    off += (bytes + 255) & ~(size_t)255;
    return p;
  };
  int* cnt = (int*)alloc((size_t)N * 4);
  int* row_ptr = (int*)alloc((size_t)(N + 1) * 4);
  int* cursor = (int*)alloc((size_t)N * 4);
  float* dinv = (float*)alloc((size_t)N * 4);
  int* partial = (int*)alloc(4 * 512);
  int* blockoff = (int*)alloc(4 * 512);
  int* csr = (int*)alloc((size_t)E * 4);
  unsigned short* Wbf = (unsigned short*)alloc((size_t)4 * 128 * 128 * 2);
  unsigned short* Abuf = (unsigned short*)alloc((size_t)N * NFEAT * 2);
  unsigned short* Bbuf = (unsigned short*)alloc((size_t)N * NFEAT * 2);
  (void)ws_size;  // total ~59 MB

  int nb = (N + 255) / 256;  // 391

  hipMemsetAsync(cnt, 0, (size_t)N * 4, stream);
  k_count<<<(E + 255) / 256, 256, 0, stream>>>(dst, cnt, E);
  k_scan1<<<nb, 256, 0, stream>>>(cnt, partial, N);
  k_scan2<<<1, 512, 0, stream>>>(partial, blockoff, nb, row_ptr, N);
  k_scan3<<<nb, 256, 0, stream>>>(cnt, blockoff, row_ptr, cursor, dinv, N);
  k_fill<<<(E + 255) / 256, 256, 0, stream>>>(src, dst, cursor, csr, E);
  k_cvtw<<<(4 * 128 * 128) / 256, 256, 0, stream>>>(W1l, W1r, W2l, W2r, Wbf);

  unsigned short* W1l_bf = Wbf;
  unsigned short* W1r_bf = Wbf + 16384;
  unsigned short* W2l_bf = Wbf + 32768;
  unsigned short* W2r_bf = Wbf + 49152;

  int gagg = (N + 3) / 4;
  int ggemm = (N + 63) / 64;

  // layer 1
  k_aggregate<true><<<gagg, 256, 0, stream>>>(x, row_ptr, csr, dinv, (unsigned int*)Abuf, N);
  k_gemm<true><<<ggemm, 256, 0, stream>>>(Abuf, x, W1l_bf, W1r_bf, b1, Bbuf, N);
  // layer 2
  k_aggregate<false><<<gagg, 256, 0, stream>>>(Bbuf, row_ptr, csr, dinv, (unsigned int*)Abuf, N);
  k_gemm<false><<<ggemm, 256, 0, stream>>>(Abuf, Bbuf, W2l_bf, W2r_bf, b2, Bbuf, N);
  // layer 3
  k_aggregate<false><<<gagg, 256, 0, stream>>>(Bbuf, row_ptr, csr, dinv, (unsigned int*)Abuf, N);
  k_layer3<<<gagg, 256, 0, stream>>>((const unsigned int*)Abuf, (const unsigned int*)Bbuf,
                                     W3l, b3, W3r, out, N);
}

// Round 2
// 593.637 us; speedup vs baseline: 1.4502x; 1.4502x over previous
//
#include <hip/hip_runtime.h>
#include <hip/hip_bf16.h>

#define NFEAT 128

typedef __attribute__((ext_vector_type(8))) short frag8;
typedef __attribute__((ext_vector_type(4))) float f32x4;

__device__ __forceinline__ unsigned short f2bf(float f) {
  unsigned int u = __builtin_bit_cast(unsigned int, f);
  u += 0x7fffu + ((u >> 16) & 1u);
  return (unsigned short)(u >> 16);
}
__device__ __forceinline__ float bf2f(unsigned short s) {
  return __builtin_bit_cast(float, ((unsigned int)s) << 16);
}
__device__ __forceinline__ unsigned int pack2(float lo, float hi) {
  return (unsigned int)f2bf(lo) | ((unsigned int)f2bf(hi) << 16);
}

// ---------------- CSR build ----------------
__global__ void k_count(const int* __restrict__ dst, int* __restrict__ cnt, int E) {
  int i = blockIdx.x * blockDim.x + threadIdx.x;
  if (i < E) atomicAdd(&cnt[dst[i]], 1);
}

__global__ void k_scan1(const int* __restrict__ cnt, int* __restrict__ partial, int n) {
  __shared__ int sm[256];
  int t = threadIdx.x, i = blockIdx.x * 256 + t;
  sm[t] = (i < n) ? cnt[i] : 0;
  __syncthreads();
  for (int off = 128; off > 0; off >>= 1) {
    if (t < off) sm[t] += sm[t + off];
    __syncthreads();
  }
  if (t == 0) partial[blockIdx.x] = sm[0];
}

__global__ void k_scan2(const int* __restrict__ partial, int* __restrict__ blockoff,
                        int nb, int* __restrict__ row_ptr, int n) {
  __shared__ int sm[512];
  int t = threadIdx.x;
  int v = (t < nb) ? partial[t] : 0;
  sm[t] = v;
  __syncthreads();
  for (int off = 1; off < 512; off <<= 1) {
    int add = (t >= off) ? sm[t - off] : 0;
    __syncthreads();
    sm[t] += add;
    __syncthreads();
  }
  if (t < nb) blockoff[t] = sm[t] - v;
  if (t == nb - 1) row_ptr[n] = sm[t];
}

__global__ void k_scan3(const int* __restrict__ cnt, const int* __restrict__ blockoff,
                        int* __restrict__ row_ptr, int* __restrict__ cursor,
                        float* __restrict__ dinv, int n) {
  __shared__ int sm[256];
  int t = threadIdx.x, i = blockIdx.x * 256 + t;
  int v = (i < n) ? cnt[i] : 0;
  sm[t] = v;
  __syncthreads();
  for (int off = 1; off < 256; off <<= 1) {
    int add = (t >= off) ? sm[t - off] : 0;
    __syncthreads();
    sm[t] += add;
    __syncthreads();
  }
  if (i < n) {
    int rp = blockoff[blockIdx.x] + sm[t] - v;
    row_ptr[i] = rp;
    cursor[i] = rp;
    dinv[i] = (v > 0) ? (1.0f / (float)v) : 0.0f;
  }
}

__global__ void k_fill(const int* __restrict__ src, const int* __restrict__ dst,
                       int* __restrict__ cursor, int* __restrict__ csr, int E) {
  int i = blockIdx.x * blockDim.x + threadIdx.x;
  if (i < E) {
    int p = atomicAdd(&cursor[dst[i]], 1);
    csr[p] = src[i];
  }
}

// ---------------- fp32 -> bf16 conversions ----------------
__global__ void k_cvtw(const float* __restrict__ w0, const float* __restrict__ w1,
                       const float* __restrict__ w2, const float* __restrict__ w3,
                       unsigned short* __restrict__ out) {
  int i = blockIdx.x * blockDim.x + threadIdx.x;  // 4 matrices of 128x128
  int m = i >> 14, off = i & 16383;
  const float* src = (m == 0) ? w0 : (m == 1) ? w1 : (m == 2) ? w2 : w3;
  out[i] = f2bf(src[off]);
}

__global__ void k_cvtx(const float* __restrict__ x, unsigned int* __restrict__ out,
                       int n_pairs) {
  int i = blockIdx.x * blockDim.x + threadIdx.x;  // one bf16-pair per thread
  if (i < n_pairs) {
    float2 v = *(const float2*)(x + (size_t)i * 2);
    out[i] = pack2(v.x, v.y);
  }
}

// ---------------- mean aggregation (gather over CSR, high-MLP) ----------------
// one wave per node. bf16 path: 4 edge-slots x 16 lanes x 16B (row=256B).
// fp32 path: 2 edge-slots x 32 lanes x 16B (row=512B). 16 edges in flight/iter.
template <bool IN_F32>
__global__ __launch_bounds__(256) void k_aggregate(
    const void* __restrict__ Xin, const int* __restrict__ row_ptr,
    const int* __restrict__ csr, const float* __restrict__ dinv,
    unsigned int* __restrict__ Aout, int n) {
  int wv = threadIdx.x >> 6, lane = threadIdx.x & 63;
  int v = blockIdx.x * 4 + wv;
  if (v >= n) return;
  int beg = row_ptr[v], end = row_ptr[v + 1];
  float dv = dinv[v];

  if constexpr (IN_F32) {
    const float* xp = (const float*)Xin;
    int slot = lane >> 5;  // 0..1
    int part = lane & 31;  // features part*4 .. part*4+3
    float acc[4] = {0.f, 0.f, 0.f, 0.f};
    for (int j = beg; j < end; j += 16) {
      float4 f[8];
#pragma unroll
      for (int b = 0; b < 8; ++b) {
        f[b] = make_float4(0.f, 0.f, 0.f, 0.f);
        int e = j + b * 2 + slot;
        if (e < end) {
          int si = csr[e];
          f[b] = *(const float4*)(xp + (size_t)si * NFEAT + part * 4);
        }
      }
#pragma unroll
      for (int b = 0; b < 8; ++b) {
        acc[0] += f[b].x; acc[1] += f[b].y; acc[2] += f[b].z; acc[3] += f[b].w;
      }
    }
#pragma unroll
    for (int k = 0; k < 4; ++k) acc[k] += __shfl_xor(acc[k], 32);
    if (slot == 0) {
      uint2 o;
      o.x = pack2(acc[0] * dv, acc[1] * dv);
      o.y = pack2(acc[2] * dv, acc[3] * dv);
      *(uint2*)(Aout + (size_t)v * (NFEAT / 2) + part * 2) = o;
    }
  } else {
    const unsigned int* xp = (const unsigned int*)Xin;
    int slot = lane >> 4;  // 0..3
    int part = lane & 15;  // features part*8 .. part*8+7
    float acc[8] = {0.f, 0.f, 0.f, 0.f, 0.f, 0.f, 0.f, 0.f};
    for (int j = beg; j < end; j += 16) {
      uint4 f[4];
#pragma unroll
      for (int b = 0; b < 4; ++b) {
        f[b] = make_uint4(0u, 0u, 0u, 0u);
        int e = j + b * 4 + slot;
        if (e < end) {
          int si = csr[e];
          f[b] = *(const uint4*)(xp + (size_t)si * (NFEAT / 2) + part * 4);
        }
      }
#pragma unroll
      for (int b = 0; b < 4; ++b) {
        acc[0] += bf2f((unsigned short)(f[b].x & 0xffffu));
        acc[1] += bf2f((unsigned short)(f[b].x >> 16));
        acc[2] += bf2f((unsigned short)(f[b].y & 0xffffu));
        acc[3] += bf2f((unsigned short)(f[b].y >> 16));
        acc[4] += bf2f((unsigned short)(f[b].z & 0xffffu));
        acc[5] += bf2f((unsigned short)(f[b].z >> 16));
        acc[6] += bf2f((unsigned short)(f[b].w & 0xffffu));
        acc[7] += bf2f((unsigned short)(f[b].w >> 16));
      }
    }
#pragma unroll
    for (int k = 0; k < 8; ++k) {
      acc[k] += __shfl_xor(acc[k], 16);
      acc[k] += __shfl_xor(acc[k], 32);
    }
    if (slot == 0) {
      uint4 o;
      o.x = pack2(acc[0] * dv, acc[1] * dv);
      o.y = pack2(acc[2] * dv, acc[3] * dv);
      o.z = pack2(acc[4] * dv, acc[5] * dv);
      o.w = pack2(acc[6] * dv, acc[7] * dv);
      *(uint4*)(Aout + (size_t)v * (NFEAT / 2) + part * 4) = o;
    }
  }
}

// ---------------- fused dual GEMM: Out = relu(A@Wl.T + bias + X@Wr.T) ----------------
template <bool X_IS_F32>
__global__ __launch_bounds__(256) void k_gemm(
    const unsigned short* __restrict__ A,   // [M][128] bf16 (aggregated)
    const void* __restrict__ X,             // [M][128] f32 or bf16 (self features)
    const unsigned short* __restrict__ Wl,  // [128][128] bf16
    const unsigned short* __restrict__ Wr,  // [128][128] bf16
    const float* __restrict__ bias,         // [128]
    unsigned short* __restrict__ Out,       // [M][128] bf16 (relu applied)
    int M) {
  int wv = threadIdx.x >> 6, lane = threadIdx.x & 63;
  int m0 = blockIdx.x * 64 + wv * 16;
  int lr = lane & 15, kq = lane >> 4;
  int row = m0 + lr;
  bool rowok = row < M;
  int kb0 = kq * 8;
  f32x4 acc[8] = {};

  {  // A part (K=128)
    const unsigned short* ap = A + (size_t)(rowok ? row : 0) * NFEAT;
#pragma unroll
    for (int kk = 0; kk < 4; ++kk) {
      int kb = kk * 32 + kb0;
      frag8 a = {};
      if (rowok) a = *(const frag8*)(ap + kb);
#pragma unroll
      for (int c = 0; c < 8; ++c) {
        frag8 b = *(const frag8*)(Wl + (size_t)(c * 16 + lr) * NFEAT + kb);
        acc[c] = __builtin_amdgcn_mfma_f32_16x16x32_bf16(a, b, acc[c], 0, 0, 0);
      }
    }
  }
  {  // X part (K=128)
#pragma unroll
    for (int kk = 0; kk < 4; ++kk) {
      int kb = kk * 32 + kb0;
      frag8 a = {};
      if (rowok) {
        if constexpr (X_IS_F32) {
          const float* xp = (const float*)X + (size_t)row * NFEAT + kb;
          float4 v0 = *(const float4*)xp;
          float4 v1 = *(const float4*)(xp + 4);
          a[0] = (short)f2bf(v0.x); a[1] = (short)f2bf(v0.y);
          a[2] = (short)f2bf(v0.z); a[3] = (short)f2bf(v0.w);
          a[4] = (short)f2bf(v1.x); a[5] = (short)f2bf(v1.y);
          a[6] = (short)f2bf(v1.z); a[7] = (short)f2bf(v1.w);
        } else {
          a = *(const frag8*)((const unsigned short*)X + (size_t)row * NFEAT + kb);
        }
      }
#pragma unroll
      for (int c = 0; c < 8; ++c) {
        frag8 b = *(const frag8*)(Wr + (size_t)(c * 16 + lr) * NFEAT + kb);
        acc[c] = __builtin_amdgcn_mfma_f32_16x16x32_bf16(a, b, acc[c], 0, 0, 0);
      }
    }
  }
#pragma unroll
  for (int c = 0; c < 8; ++c) {
#pragma unroll
    for (int r = 0; r < 4; ++r) {
      int orow = m0 + kq * 4 + r;
      if (orow < M) {
        int ocol = c * 16 + lr;
        float val = acc[c][r] + bias[ocol];
        val = fmaxf(val, 0.f);
        Out[(size_t)orow * NFEAT + ocol] = f2bf(val);
      }
    }
  }
}

// ---------------- layer 3 (N_CLS=7) + log_softmax ----------------
__global__ void k_layer3(const unsigned int* __restrict__ A,
                         const unsigned int* __restrict__ H,
                         const float* __restrict__ W3l, const float* __restrict__ b3,
                         const float* __restrict__ W3r, float* __restrict__ out, int n) {
  int wv = threadIdx.x >> 6, lane = threadIdx.x & 63;
  int v = blockIdx.x * 4 + wv;
  if (v >= n) return;
  unsigned int ua = A[(size_t)v * (NFEAT / 2) + lane];
  unsigned int uh = H[(size_t)v * (NFEAT / 2) + lane];
  float a0 = bf2f((unsigned short)(ua & 0xffffu)), a1 = bf2f((unsigned short)(ua >> 16));
  float h0 = bf2f((unsigned short)(uh & 0xffffu)), h1 = bf2f((unsigned short)(uh >> 16));
  float s[7];
#pragma unroll
  for (int c = 0; c < 7; ++c) {
    float2 wl = *(const float2*)(W3l + c * NFEAT + lane * 2);
    float2 wr = *(const float2*)(W3r + c * NFEAT + lane * 2);
    s[c] = a0 * wl.x + a1 * wl.y + h0 * wr.x + h1 * wr.y;
  }
#pragma unroll
  for (int off = 32; off > 0; off >>= 1) {
#pragma unroll
    for (int c = 0; c < 7; ++c) s[c] += __shfl_xor(s[c], off);
  }
  float z[7], mx = -1e30f;
#pragma unroll
  for (int c = 0; c < 7; ++c) {
    z[c] = s[c] + b3[c];
    mx = fmaxf(mx, z[c]);
  }
  float se = 0.f;
#pragma unroll
  for (int c = 0; c < 7; ++c) se += __expf(z[c] - mx);
  float lse = mx + __logf(se);
  float val = z[0];
#pragma unroll
  for (int c = 1; c < 7; ++c) val = (lane == c) ? z[c] : val;
  if (lane < 7) out[(size_t)v * 7 + lane] = val - lse;
}

// ---------------- launch ----------------
extern "C" void kernel_launch(void* const* d_in, const int* in_sizes, int n_in,
                              void* d_out, int out_size, void* d_ws, size_t ws_size,
                              hipStream_t stream) {
  const float* x = (const float*)d_in[0];
  const int* ei = (const int*)d_in[1];
  const float* W1l = (const float*)d_in[2];
  const float* b1 = (const float*)d_in[3];
  const float* W1r = (const float*)d_in[4];
  const float* W2l = (const float*)d_in[5];
  const float* b2 = (const float*)d_in[6];
  const float* W2r = (const float*)d_in[7];
  const float* W3l = (const float*)d_in[8];
  const float* b3 = (const float*)d_in[9];
  const float* W3r = (const float*)d_in[10];
  float* out = (float*)d_out;

  int N = in_sizes[0] / NFEAT;
  int E = in_sizes[1] / 2;
  const int* src = ei;
  const int* dst = ei + E;

  char* ws = (char*)d_ws;
  size_t off = 0;
  auto alloc = [&](size_t bytes) {
    void* p = (void*)(ws + off);
    off += (bytes + 255) & ~(size_t)255;
    return p;
  };
  int* cnt = (int*)alloc((size_t)N * 4);
  int* row_ptr = (int*)alloc((size_t)(N + 1) * 4);
  int* cursor = (int*)alloc((size_t)N * 4);
  float* dinv = (float*)alloc((size_t)N * 4);
  int* partial = (int*)alloc(4 * 512);
  int* blockoff = (int*)alloc(4 * 512);
  int* csr = (int*)alloc((size_t)E * 4);
  unsigned short* Wbf = (unsigned short*)alloc((size_t)4 * 128 * 128 * 2);
  unsigned short* Abuf = (unsigned short*)alloc((size_t)N * NFEAT * 2);
  unsigned short* Bbuf = (unsigned short*)alloc((size_t)N * NFEAT * 2);
  size_t off_base = off;
  unsigned short* Xbf = (unsigned short*)alloc((size_t)N * NFEAT * 2);
  bool use_xbf = (off <= ws_size);
  if (!use_xbf) off = off_base;

  int nb = (N + 255) / 256;  // 391

  hipMemsetAsync(cnt, 0, (size_t)N * 4, stream);
  k_count<<<(E + 255) / 256, 256, 0, stream>>>(dst, cnt, E);
  k_scan1<<<nb, 256, 0, stream>>>(cnt, partial, N);
  k_scan2<<<1, 512, 0, stream>>>(partial, blockoff, nb, row_ptr, N);
  k_scan3<<<nb, 256, 0, stream>>>(cnt, blockoff, row_ptr, cursor, dinv, N);
  k_fill<<<(E + 255) / 256, 256, 0, stream>>>(src, dst, cursor, csr, E);
  k_cvtw<<<(4 * 128 * 128) / 256, 256, 0, stream>>>(W1l, W1r, W2l, W2r, Wbf);
  if (use_xbf) {
    int npairs = N * (NFEAT / 2);
    k_cvtx<<<(npairs + 255) / 256, 256, 0, stream>>>(x, (unsigned int*)Xbf, npairs);
  }

  unsigned short* W1l_bf = Wbf;
  unsigned short* W1r_bf = Wbf + 16384;
  unsigned short* W2l_bf = Wbf + 32768;
  unsigned short* W2r_bf = Wbf + 49152;

  int gagg = (N + 3) / 4;
  int ggemm = (N + 63) / 64;

  // layer 1
  if (use_xbf) {
    k_aggregate<false><<<gagg, 256, 0, stream>>>(Xbf, row_ptr, csr, dinv,
                                                 (unsigned int*)Abuf, N);
    k_gemm<false><<<ggemm, 256, 0, stream>>>(Abuf, Xbf, W1l_bf, W1r_bf, b1, Bbuf, N);
  } else {
    k_aggregate<true><<<gagg, 256, 0, stream>>>(x, row_ptr, csr, dinv,
                                                (unsigned int*)Abuf, N);
    k_gemm<true><<<ggemm, 256, 0, stream>>>(Abuf, x, W1l_bf, W1r_bf, b1, Bbuf, N);
  }
  // layer 2
  k_aggregate<false><<<gagg, 256, 0, stream>>>(Bbuf, row_ptr, csr, dinv,
                                               (unsigned int*)Abuf, N);
  k_gemm<false><<<ggemm, 256, 0, stream>>>(Abuf, Bbuf, W2l_bf, W2r_bf, b2, Bbuf, N);
  // layer 3
  k_aggregate<false><<<gagg, 256, 0, stream>>>(Bbuf, row_ptr, csr, dinv,
                                               (unsigned int*)Abuf, N);
  k_layer3<<<gagg, 256, 0, stream>>>((const unsigned int*)Abuf, (const unsigned int*)Bbuf,
                                     W3l, b3, W3r, out, N);
}

// Round 3
// 444.054 us; speedup vs baseline: 1.9386x; 1.3369x over previous
//
#include <hip/hip_runtime.h>
#include <hip/hip_bf16.h>

#define NFEAT 128

typedef __attribute__((ext_vector_type(8))) short frag8;
typedef __attribute__((ext_vector_type(4))) float f32x4;

__device__ __forceinline__ unsigned short f2bf(float f) {
  unsigned int u = __builtin_bit_cast(unsigned int, f);
  u += 0x7fffu + ((u >> 16) & 1u);
  return (unsigned short)(u >> 16);
}
__device__ __forceinline__ float bf2f(unsigned short s) {
  return __builtin_bit_cast(float, ((unsigned int)s) << 16);
}
__device__ __forceinline__ unsigned int pack2(float lo, float hi) {
  return (unsigned int)f2bf(lo) | ((unsigned int)f2bf(hi) << 16);
}

// ================= CSR build: two-level bucketed counting sort =================
// bucket = dst >> 8 (256 nodes per bucket). NB = (N+255)>>8 <= 512.

__global__ __launch_bounds__(256) void k_bucket_count(
    const int* __restrict__ dst, int* __restrict__ bucket_cnt, int E, int NB, int chunk) {
  __shared__ int hist[512];
  int t = threadIdx.x;
  hist[t] = 0;
  hist[t + 256] = 0;
  __syncthreads();
  int beg = blockIdx.x * chunk, end = min(beg + chunk, E);
  for (int i = beg + t; i < end; i += 256) atomicAdd(&hist[dst[i] >> 8], 1);
  __syncthreads();
  for (int k = t; k < NB; k += 256)
    if (hist[k]) atomicAdd(&bucket_cnt[k], hist[k]);
}

__global__ void k_bucket_scan(const int* __restrict__ bucket_cnt,
                              int* __restrict__ bucket_base,
                              int* __restrict__ bucket_cursor, int NB, int E) {
  __shared__ int sm[512];
  int t = threadIdx.x;
  int v = (t < NB) ? bucket_cnt[t] : 0;
  sm[t] = v;
  __syncthreads();
  for (int off = 1; off < 512; off <<= 1) {
    int add = (t >= off) ? sm[t - off] : 0;
    __syncthreads();
    sm[t] += add;
    __syncthreads();
  }
  int excl = sm[t] - v;
  if (t < NB) {
    bucket_base[t] = excl;
    bucket_cursor[t] = excl;
  }
  if (t == 0) bucket_base[NB] = E;
}

__global__ __launch_bounds__(256) void k_bucket_fill(
    const int* __restrict__ src, const int* __restrict__ dst,
    int* __restrict__ bucket_cursor, unsigned int* __restrict__ tmp,
    int E, int NB, int chunk) {
  __shared__ int hist[512];
  __shared__ int cur[512];
  int t = threadIdx.x;
  hist[t] = 0;
  hist[t + 256] = 0;
  __syncthreads();
  int beg = blockIdx.x * chunk, end = min(beg + chunk, E);
  for (int i = beg + t; i < end; i += 256) atomicAdd(&hist[dst[i] >> 8], 1);
  __syncthreads();
  for (int k = t; k < 512; k += 256)
    cur[k] = (k < NB && hist[k]) ? atomicAdd(&bucket_cursor[k], hist[k]) : 0;
  __syncthreads();
  for (int i = beg + t; i < end; i += 256) {
    int d = dst[i];
    int p = atomicAdd(&cur[d >> 8], 1);
    tmp[p] = (((unsigned int)(d & 255)) << 24) | (unsigned int)src[i];
  }
}

// one block per bucket: counting sort of the bucket's edges over its 256 nodes
__global__ __launch_bounds__(256) void k_local_sort(
    const unsigned int* __restrict__ tmp, const int* __restrict__ bucket_base,
    int* __restrict__ csr, int* __restrict__ row_ptr, float* __restrict__ dinv,
    int N, int E) {
  __shared__ int cnt[256];
  __shared__ int scan_s[256];
  int b = blockIdx.x, t = threadIdx.x;
  int base = bucket_base[b];
  int cnt_b = bucket_base[b + 1] - base;
  cnt[t] = 0;
  __syncthreads();
  for (int i = t; i < cnt_b; i += 256) atomicAdd(&cnt[tmp[base + i] >> 24], 1);
  __syncthreads();
  int v = cnt[t];
  scan_s[t] = v;
  __syncthreads();
  for (int off = 1; off < 256; off <<= 1) {
    int add = (t >= off) ? scan_s[t - off] : 0;
    __syncthreads();
    scan_s[t] += add;
    __syncthreads();
  }
  int excl = scan_s[t] - v;
  int node = b * 256 + t;
  if (node <= N) row_ptr[node] = base + excl;
  if (node < N) dinv[node] = (v > 0) ? (1.0f / (float)v) : 0.0f;
  __syncthreads();
  cnt[t] = base + excl;  // becomes running cursor
  __syncthreads();
  for (int i = t; i < cnt_b; i += 256) {
    unsigned int u = tmp[base + i];
    int q = atomicAdd(&cnt[u >> 24], 1);
    csr[q] = (int)(u & 0x00FFFFFFu);
  }
}

// ---------------- fp32 -> bf16 conversions ----------------
__global__ void k_cvtw(const float* __restrict__ w0, const float* __restrict__ w1,
                       const float* __restrict__ w2, const float* __restrict__ w3,
                       unsigned short* __restrict__ out) {
  int i = blockIdx.x * blockDim.x + threadIdx.x;  // 4 matrices of 128x128
  int m = i >> 14, off = i & 16383;
  const float* src = (m == 0) ? w0 : (m == 1) ? w1 : (m == 2) ? w2 : w3;
  out[i] = f2bf(src[off]);
}

__global__ void k_cvtx(const float* __restrict__ x, unsigned int* __restrict__ out,
                       int n_pairs) {
  int i = blockIdx.x * blockDim.x + threadIdx.x;
  if (i < n_pairs) {
    float2 v = *(const float2*)(x + (size_t)i * 2);
    out[i] = pack2(v.x, v.y);
  }
}

// ---------------- mean aggregation (gather over CSR, high-MLP) ----------------
template <bool IN_F32>
__global__ __launch_bounds__(256) void k_aggregate(
    const void* __restrict__ Xin, const int* __restrict__ row_ptr,
    const int* __restrict__ csr, const float* __restrict__ dinv,
    unsigned int* __restrict__ Aout, int n) {
  int wv = threadIdx.x >> 6, lane = threadIdx.x & 63;
  int v = blockIdx.x * 4 + wv;
  if (v >= n) return;
  int beg = row_ptr[v], end = row_ptr[v + 1];
  float dv = dinv[v];

  if constexpr (IN_F32) {
    const float* xp = (const float*)Xin;
    int slot = lane >> 5;
    int part = lane & 31;
    float acc[4] = {0.f, 0.f, 0.f, 0.f};
    for (int j = beg; j < end; j += 16) {
      float4 f[8];
#pragma unroll
      for (int b = 0; b < 8; ++b) {
        f[b] = make_float4(0.f, 0.f, 0.f, 0.f);
        int e = j + b * 2 + slot;
        if (e < end) {
          int si = csr[e];
          f[b] = *(const float4*)(xp + (size_t)si * NFEAT + part * 4);
        }
      }
#pragma unroll
      for (int b = 0; b < 8; ++b) {
        acc[0] += f[b].x; acc[1] += f[b].y; acc[2] += f[b].z; acc[3] += f[b].w;
      }
    }
#pragma unroll
    for (int k = 0; k < 4; ++k) acc[k] += __shfl_xor(acc[k], 32);
    if (slot == 0) {
      uint2 o;
      o.x = pack2(acc[0] * dv, acc[1] * dv);
      o.y = pack2(acc[2] * dv, acc[3] * dv);
      *(uint2*)(Aout + (size_t)v * (NFEAT / 2) + part * 2) = o;
    }
  } else {
    const unsigned int* xp = (const unsigned int*)Xin;
    int slot = lane >> 4;
    int part = lane & 15;
    float acc[8] = {0.f, 0.f, 0.f, 0.f, 0.f, 0.f, 0.f, 0.f};
    for (int j = beg; j < end; j += 16) {
      uint4 f[4];
#pragma unroll
      for (int b = 0; b < 4; ++b) {
        f[b] = make_uint4(0u, 0u, 0u, 0u);
        int e = j + b * 4 + slot;
        if (e < end) {
          int si = csr[e];
          f[b] = *(const uint4*)(xp + (size_t)si * (NFEAT / 2) + part * 4);
        }
      }
#pragma unroll
      for (int b = 0; b < 4; ++b) {
        acc[0] += bf2f((unsigned short)(f[b].x & 0xffffu));
        acc[1] += bf2f((unsigned short)(f[b].x >> 16));
        acc[2] += bf2f((unsigned short)(f[b].y & 0xffffu));
        acc[3] += bf2f((unsigned short)(f[b].y >> 16));
        acc[4] += bf2f((unsigned short)(f[b].z & 0xffffu));
        acc[5] += bf2f((unsigned short)(f[b].z >> 16));
        acc[6] += bf2f((unsigned short)(f[b].w & 0xffffu));
        acc[7] += bf2f((unsigned short)(f[b].w >> 16));
      }
    }
#pragma unroll
    for (int k = 0; k < 8; ++k) {
      acc[k] += __shfl_xor(acc[k], 16);
      acc[k] += __shfl_xor(acc[k], 32);
    }
    if (slot == 0) {
      uint4 o;
      o.x = pack2(acc[0] * dv, acc[1] * dv);
      o.y = pack2(acc[2] * dv, acc[3] * dv);
      o.z = pack2(acc[4] * dv, acc[5] * dv);
      o.w = pack2(acc[6] * dv, acc[7] * dv);
      *(uint4*)(Aout + (size_t)v * (NFEAT / 2) + part * 4) = o;
    }
  }
}

// ---------------- fused dual GEMM: Out = relu(A@Wl.T + bias + X@Wr.T) ----------------
template <bool X_IS_F32>
__global__ __launch_bounds__(256) void k_gemm(
    const unsigned short* __restrict__ A, const void* __restrict__ X,
    const unsigned short* __restrict__ Wl, const unsigned short* __restrict__ Wr,
    const float* __restrict__ bias, unsigned short* __restrict__ Out, int M) {
  int wv = threadIdx.x >> 6, lane = threadIdx.x & 63;
  int m0 = blockIdx.x * 64 + wv * 16;
  int lr = lane & 15, kq = lane >> 4;
  int row = m0 + lr;
  bool rowok = row < M;
  int kb0 = kq * 8;
  f32x4 acc[8] = {};

  {
    const unsigned short* ap = A + (size_t)(rowok ? row : 0) * NFEAT;
#pragma unroll
    for (int kk = 0; kk < 4; ++kk) {
      int kb = kk * 32 + kb0;
      frag8 a = {};
      if (rowok) a = *(const frag8*)(ap + kb);
#pragma unroll
      for (int c = 0; c < 8; ++c) {
        frag8 b = *(const frag8*)(Wl + (size_t)(c * 16 + lr) * NFEAT + kb);
        acc[c] = __builtin_amdgcn_mfma_f32_16x16x32_bf16(a, b, acc[c], 0, 0, 0);
      }
    }
  }
  {
#pragma unroll
    for (int kk = 0; kk < 4; ++kk) {
      int kb = kk * 32 + kb0;
      frag8 a = {};
      if (rowok) {
        if constexpr (X_IS_F32) {
          const float* xp = (const float*)X + (size_t)row * NFEAT + kb;
          float4 v0 = *(const float4*)xp;
          float4 v1 = *(const float4*)(xp + 4);
          a[0] = (short)f2bf(v0.x); a[1] = (short)f2bf(v0.y);
          a[2] = (short)f2bf(v0.z); a[3] = (short)f2bf(v0.w);
          a[4] = (short)f2bf(v1.x); a[5] = (short)f2bf(v1.y);
          a[6] = (short)f2bf(v1.z); a[7] = (short)f2bf(v1.w);
        } else {
          a = *(const frag8*)((const unsigned short*)X + (size_t)row * NFEAT + kb);
        }
      }
#pragma unroll
      for (int c = 0; c < 8; ++c) {
        frag8 b = *(const frag8*)(Wr + (size_t)(c * 16 + lr) * NFEAT + kb);
        acc[c] = __builtin_amdgcn_mfma_f32_16x16x32_bf16(a, b, acc[c], 0, 0, 0);
      }
    }
  }
#pragma unroll
  for (int c = 0; c < 8; ++c) {
#pragma unroll
    for (int r = 0; r < 4; ++r) {
      int orow = m0 + kq * 4 + r;
      if (orow < M) {
        int ocol = c * 16 + lr;
        float val = acc[c][r] + bias[ocol];
        val = fmaxf(val, 0.f);
        Out[(size_t)orow * NFEAT + ocol] = f2bf(val);
      }
    }
  }
}

// ---------------- layer 3 (N_CLS=7) + log_softmax ----------------
__global__ void k_layer3(const unsigned int* __restrict__ A,
                         const unsigned int* __restrict__ H,
                         const float* __restrict__ W3l, const float* __restrict__ b3,
                         const float* __restrict__ W3r, float* __restrict__ out, int n) {
  int wv = threadIdx.x >> 6, lane = threadIdx.x & 63;
  int v = blockIdx.x * 4 + wv;
  if (v >= n) return;
  unsigned int ua = A[(size_t)v * (NFEAT / 2) + lane];
  unsigned int uh = H[(size_t)v * (NFEAT / 2) + lane];
  float a0 = bf2f((unsigned short)(ua & 0xffffu)), a1 = bf2f((unsigned short)(ua >> 16));
  float h0 = bf2f((unsigned short)(uh & 0xffffu)), h1 = bf2f((unsigned short)(uh >> 16));
  float s[7];
#pragma unroll
  for (int c = 0; c < 7; ++c) {
    float2 wl = *(const float2*)(W3l + c * NFEAT + lane * 2);
    float2 wr = *(const float2*)(W3r + c * NFEAT + lane * 2);
    s[c] = a0 * wl.x + a1 * wl.y + h0 * wr.x + h1 * wr.y;
  }
#pragma unroll
  for (int off = 32; off > 0; off >>= 1) {
#pragma unroll
    for (int c = 0; c < 7; ++c) s[c] += __shfl_xor(s[c], off);
  }
  float z[7], mx = -1e30f;
#pragma unroll
  for (int c = 0; c < 7; ++c) {
    z[c] = s[c] + b3[c];
    mx = fmaxf(mx, z[c]);
  }
  float se = 0.f;
#pragma unroll
  for (int c = 0; c < 7; ++c) se += __expf(z[c] - mx);
  float lse = mx + __logf(se);
  float val = z[0];
#pragma unroll
  for (int c = 1; c < 7; ++c) val = (lane == c) ? z[c] : val;
  if (lane < 7) out[(size_t)v * 7 + lane] = val - lse;
}

// ---------------- launch ----------------
extern "C" void kernel_launch(void* const* d_in, const int* in_sizes, int n_in,
                              void* d_out, int out_size, void* d_ws, size_t ws_size,
                              hipStream_t stream) {
  const float* x = (const float*)d_in[0];
  const int* ei = (const int*)d_in[1];
  const float* W1l = (const float*)d_in[2];
  const float* b1 = (const float*)d_in[3];
  const float* W1r = (const float*)d_in[4];
  const float* W2l = (const float*)d_in[5];
  const float* b2 = (const float*)d_in[6];
  const float* W2r = (const float*)d_in[7];
  const float* W3l = (const float*)d_in[8];
  const float* b3 = (const float*)d_in[9];
  const float* W3r = (const float*)d_in[10];
  float* out = (float*)d_out;

  int N = in_sizes[0] / NFEAT;
  int E = in_sizes[1] / 2;
  const int* src = ei;
  const int* dst = ei + E;

  char* ws = (char*)d_ws;
  size_t off = 0;
  auto alloc = [&](size_t bytes) {
    void* p = (void*)(ws + off);
    off += (bytes + 255) & ~(size_t)255;
    return p;
  };
  int* row_ptr = (int*)alloc((size_t)(N + 1) * 4);
  float* dinv = (float*)alloc((size_t)N * 4);
  int* bucket_cnt = (int*)alloc(512 * 4);
  int* bucket_base = (int*)alloc(513 * 4);
  int* bucket_cursor = (int*)alloc(512 * 4);
  int* csr = (int*)alloc((size_t)E * 4);
  unsigned short* Wbf = (unsigned short*)alloc((size_t)4 * 128 * 128 * 2);
  unsigned short* Abuf = (unsigned short*)alloc((size_t)N * NFEAT * 2);
  unsigned short* Bbuf = (unsigned short*)alloc((size_t)N * NFEAT * 2);
  size_t off_base = off;
  unsigned short* Xbf = (unsigned short*)alloc((size_t)N * NFEAT * 2);
  bool use_xbf = (off <= ws_size);
  if (!use_xbf) off = off_base;
  unsigned int* tmp = (unsigned int*)Abuf;  // aliased: tmp only live during CSR build

  int NB = (N + 255) >> 8;       // 391 for N=100000
  int chunk = (E + 255) / 256;   // per-block edge chunk for 256 blocks

  hipMemsetAsync(bucket_cnt, 0, 512 * 4, stream);
  k_bucket_count<<<256, 256, 0, stream>>>(dst, bucket_cnt, E, NB, chunk);
  k_bucket_scan<<<1, 512, 0, stream>>>(bucket_cnt, bucket_base, bucket_cursor, NB, E);
  k_bucket_fill<<<256, 256, 0, stream>>>(src, dst, bucket_cursor, tmp, E, NB, chunk);
  k_local_sort<<<NB, 256, 0, stream>>>(tmp, bucket_base, csr, row_ptr, dinv, N, E);
  k_cvtw<<<(4 * 128 * 128) / 256, 256, 0, stream>>>(W1l, W1r, W2l, W2r, Wbf);
  if (use_xbf) {
    int npairs = N * (NFEAT / 2);
    k_cvtx<<<(npairs + 255) / 256, 256, 0, stream>>>(x, (unsigned int*)Xbf, npairs);
  }

  unsigned short* W1l_bf = Wbf;
  unsigned short* W1r_bf = Wbf + 16384;
  unsigned short* W2l_bf = Wbf + 32768;
  unsigned short* W2r_bf = Wbf + 49152;

  int gagg = (N + 3) / 4;
  int ggemm = (N + 63) / 64;

  // layer 1
  if (use_xbf) {
    k_aggregate<false><<<gagg, 256, 0, stream>>>(Xbf, row_ptr, csr, dinv,
                                                 (unsigned int*)Abuf, N);
    k_gemm<false><<<ggemm, 256, 0, stream>>>(Abuf, Xbf, W1l_bf, W1r_bf, b1, Bbuf, N);
  } else {
    k_aggregate<true><<<gagg, 256, 0, stream>>>(x, row_ptr, csr, dinv,
                                                (unsigned int*)Abuf, N);
    k_gemm<true><<<ggemm, 256, 0, stream>>>(Abuf, x, W1l_bf, W1r_bf, b1, Bbuf, N);
  }
  // layer 2
  k_aggregate<false><<<gagg, 256, 0, stream>>>(Bbuf, row_ptr, csr, dinv,
                                               (unsigned int*)Abuf, N);
  k_gemm<false><<<ggemm, 256, 0, stream>>>(Abuf, Bbuf, W2l_bf, W2r_bf, b2, Bbuf, N);
  // layer 3
  k_aggregate<false><<<gagg, 256, 0, stream>>>(Bbuf, row_ptr, csr, dinv,
                                               (unsigned int*)Abuf, N);
  k_layer3<<<gagg, 256, 0, stream>>>((const unsigned int*)Abuf, (const unsigned int*)Bbuf,
                                     W3l, b3, W3r, out, N);
}

// Round 4
// 375.426 us; speedup vs baseline: 2.2930x; 1.1828x over previous
//
#include <hip/hip_runtime.h>
#include <hip/hip_bf16.h>

#define NFEAT 128

typedef __attribute__((ext_vector_type(8))) short frag8;
typedef __attribute__((ext_vector_type(4))) float f32x4;

__device__ __forceinline__ unsigned short f2bf(float f) {
  unsigned int u = __builtin_bit_cast(unsigned int, f);
  u += 0x7fffu + ((u >> 16) & 1u);
  return (unsigned short)(u >> 16);
}
__device__ __forceinline__ float bf2f(unsigned short s) {
  return __builtin_bit_cast(float, ((unsigned int)s) << 16);
}
__device__ __forceinline__ unsigned int pack2(float lo, float hi) {
  return (unsigned int)f2bf(lo) | ((unsigned int)f2bf(hi) << 16);
}

// ================= CSR build: two-level bucketed counting sort =================
__global__ __launch_bounds__(256) void k_bucket_count(
    const int* __restrict__ dst, int* __restrict__ bucket_cnt, int E, int NB, int chunk) {
  __shared__ int hist[512];
  int t = threadIdx.x;
  hist[t] = 0;
  hist[t + 256] = 0;
  __syncthreads();
  int beg = blockIdx.x * chunk, end = min(beg + chunk, E);
  for (int i = beg + t; i < end; i += 256) atomicAdd(&hist[dst[i] >> 8], 1);
  __syncthreads();
  for (int k = t; k < NB; k += 256)
    if (hist[k]) atomicAdd(&bucket_cnt[k], hist[k]);
}

__global__ void k_bucket_scan(const int* __restrict__ bucket_cnt,
                              int* __restrict__ bucket_base,
                              int* __restrict__ bucket_cursor, int NB, int E) {
  __shared__ int sm[512];
  int t = threadIdx.x;
  int v = (t < NB) ? bucket_cnt[t] : 0;
  sm[t] = v;
  __syncthreads();
  for (int off = 1; off < 512; off <<= 1) {
    int add = (t >= off) ? sm[t - off] : 0;
    __syncthreads();
    sm[t] += add;
    __syncthreads();
  }
  int excl = sm[t] - v;
  if (t < NB) {
    bucket_base[t] = excl;
    bucket_cursor[t] = excl;
  }
  if (t == 0) bucket_base[NB] = E;
}

__global__ __launch_bounds__(256) void k_bucket_fill(
    const int* __restrict__ src, const int* __restrict__ dst,
    int* __restrict__ bucket_cursor, unsigned int* __restrict__ tmp,
    int E, int NB, int chunk) {
  __shared__ int hist[512];
  __shared__ int cur[512];
  int t = threadIdx.x;
  hist[t] = 0;
  hist[t + 256] = 0;
  __syncthreads();
  int beg = blockIdx.x * chunk, end = min(beg + chunk, E);
  for (int i = beg + t; i < end; i += 256) atomicAdd(&hist[dst[i] >> 8], 1);
  __syncthreads();
  for (int k = t; k < 512; k += 256)
    cur[k] = (k < NB && hist[k]) ? atomicAdd(&bucket_cursor[k], hist[k]) : 0;
  __syncthreads();
  for (int i = beg + t; i < end; i += 256) {
    int d = dst[i];
    int p = atomicAdd(&cur[d >> 8], 1);
    tmp[p] = (((unsigned int)(d & 255)) << 24) | (unsigned int)src[i];
  }
}

__global__ __launch_bounds__(256) void k_local_sort(
    const unsigned int* __restrict__ tmp, const int* __restrict__ bucket_base,
    int* __restrict__ csr, int* __restrict__ row_ptr, float* __restrict__ dinv,
    int N, int E) {
  __shared__ int cnt[256];
  __shared__ int scan_s[256];
  int b = blockIdx.x, t = threadIdx.x;
  int base = bucket_base[b];
  int cnt_b = bucket_base[b + 1] - base;
  cnt[t] = 0;
  __syncthreads();
  for (int i = t; i < cnt_b; i += 256) atomicAdd(&cnt[tmp[base + i] >> 24], 1);
  __syncthreads();
  int v = cnt[t];
  scan_s[t] = v;
  __syncthreads();
  for (int off = 1; off < 256; off <<= 1) {
    int add = (t >= off) ? scan_s[t - off] : 0;
    __syncthreads();
    scan_s[t] += add;
    __syncthreads();
  }
  int excl = scan_s[t] - v;
  int node = b * 256 + t;
  if (node <= N) row_ptr[node] = base + excl;
  if (node < N) dinv[node] = (v > 0) ? (1.0f / (float)v) : 0.0f;
  __syncthreads();
  cnt[t] = base + excl;  // running cursor
  __syncthreads();
  for (int i = t; i < cnt_b; i += 256) {
    unsigned int u = tmp[base + i];
    int q = atomicAdd(&cnt[u >> 24], 1);
    csr[q] = (int)(u & 0x00FFFFFFu);
  }
}

// ---------------- fp32 -> bf16 conversions ----------------
__global__ void k_cvtw(const float* __restrict__ w0, const float* __restrict__ w1,
                       const float* __restrict__ w2, const float* __restrict__ w3,
                       unsigned short* __restrict__ out) {
  int i = blockIdx.x * blockDim.x + threadIdx.x;
  int m = i >> 14, off = i & 16383;
  const float* src = (m == 0) ? w0 : (m == 1) ? w1 : (m == 2) ? w2 : w3;
  out[i] = f2bf(src[off]);
}

__global__ void k_cvtx(const float* __restrict__ x, unsigned int* __restrict__ out,
                       int n_pairs) {
  int i = blockIdx.x * blockDim.x + threadIdx.x;
  if (i < n_pairs) {
    float2 v = *(const float2*)(x + (size_t)i * 2);
    out[i] = pack2(v.x, v.y);
  }
}

// ---------------- mean aggregation (gather over CSR, high-MLP) ----------------
template <bool IN_F32>
__global__ __launch_bounds__(256) void k_aggregate(
    const void* __restrict__ Xin, const int* __restrict__ row_ptr,
    const int* __restrict__ csr, const float* __restrict__ dinv,
    unsigned int* __restrict__ Aout, int n) {
  int wv = threadIdx.x >> 6, lane = threadIdx.x & 63;
  int v = blockIdx.x * 4 + wv;
  if (v >= n) return;
  int beg = row_ptr[v], end = row_ptr[v + 1];
  float dv = dinv[v];

  if constexpr (IN_F32) {
    const float* xp = (const float*)Xin;
    int slot = lane >> 5;
    int part = lane & 31;
    float acc[4] = {0.f, 0.f, 0.f, 0.f};
    for (int j = beg; j < end; j += 16) {
      float4 f[8];
#pragma unroll
      for (int b = 0; b < 8; ++b) {
        f[b] = make_float4(0.f, 0.f, 0.f, 0.f);
        int e = j + b * 2 + slot;
        if (e < end) {
          int si = csr[e];
          f[b] = *(const float4*)(xp + (size_t)si * NFEAT + part * 4);
        }
      }
#pragma unroll
      for (int b = 0; b < 8; ++b) {
        acc[0] += f[b].x; acc[1] += f[b].y; acc[2] += f[b].z; acc[3] += f[b].w;
      }
    }
#pragma unroll
    for (int k = 0; k < 4; ++k) acc[k] += __shfl_xor(acc[k], 32);
    if (slot == 0) {
      uint2 o;
      o.x = pack2(acc[0] * dv, acc[1] * dv);
      o.y = pack2(acc[2] * dv, acc[3] * dv);
      *(uint2*)(Aout + (size_t)v * (NFEAT / 2) + part * 2) = o;
    }
  } else {
    const unsigned int* xp = (const unsigned int*)Xin;
    int slot = lane >> 4;
    int part = lane & 15;
    float acc[8] = {0.f, 0.f, 0.f, 0.f, 0.f, 0.f, 0.f, 0.f};
    for (int j = beg; j < end; j += 16) {
      uint4 f[4];
#pragma unroll
      for (int b = 0; b < 4; ++b) {
        f[b] = make_uint4(0u, 0u, 0u, 0u);
        int e = j + b * 4 + slot;
        if (e < end) {
          int si = csr[e];
          f[b] = *(const uint4*)(xp + (size_t)si * (NFEAT / 2) + part * 4);
        }
      }
#pragma unroll
      for (int b = 0; b < 4; ++b) {
        acc[0] += bf2f((unsigned short)(f[b].x & 0xffffu));
        acc[1] += bf2f((unsigned short)(f[b].x >> 16));
        acc[2] += bf2f((unsigned short)(f[b].y & 0xffffu));
        acc[3] += bf2f((unsigned short)(f[b].y >> 16));
        acc[4] += bf2f((unsigned short)(f[b].z & 0xffffu));
        acc[5] += bf2f((unsigned short)(f[b].z >> 16));
        acc[6] += bf2f((unsigned short)(f[b].w & 0xffffu));
        acc[7] += bf2f((unsigned short)(f[b].w >> 16));
      }
    }
#pragma unroll
    for (int k = 0; k < 8; ++k) {
      acc[k] += __shfl_xor(acc[k], 16);
      acc[k] += __shfl_xor(acc[k], 32);
    }
    if (slot == 0) {
      uint4 o;
      o.x = pack2(acc[0] * dv, acc[1] * dv);
      o.y = pack2(acc[2] * dv, acc[3] * dv);
      o.z = pack2(acc[4] * dv, acc[5] * dv);
      o.w = pack2(acc[6] * dv, acc[7] * dv);
      *(uint4*)(Aout + (size_t)v * (NFEAT / 2) + part * 4) = o;
    }
  }
}

// ---------------- fused dual GEMM: Out = relu(A@Wl.T + bias + X@Wr.T) ----------------
// Persistent register-resident weights: wave wv owns output cols [32*wv, 32*wv+32).
// Block of 4 waves covers a 16-row tile; grid-stride over tiles. Weights (16 frag8
// = 64 VGPR/wave) loaded ONCE. Inner loop: 8 independent 16B loads -> 16 MFMAs.
// __syncthreads between tile loads and stores makes in-place (Out==X) safe.
template <bool X_IS_F32>
__global__ __launch_bounds__(256, 4) void k_gemm(
    const unsigned short* __restrict__ A, const void* __restrict__ X,
    const unsigned short* __restrict__ Wl, const unsigned short* __restrict__ Wr,
    const float* __restrict__ bias, unsigned short* __restrict__ Out,
    int M, int ntiles) {
  int wv = threadIdx.x >> 6, lane = threadIdx.x & 63;
  int lr = lane & 15, kq = lane >> 4;
  int kb0 = kq * 8;

  // preload this wave's weight fragments (cols c0=2wv, c1=2wv+1)
  frag8 wl[2][4], wr[2][4];
  float bias_c[2];
#pragma unroll
  for (int ci = 0; ci < 2; ++ci) {
    int wrow = (wv * 2 + ci) * 16 + lr;  // output col = weight row
    bias_c[ci] = bias[wrow];
#pragma unroll
    for (int kk = 0; kk < 4; ++kk) {
      wl[ci][kk] = *(const frag8*)(Wl + (size_t)wrow * NFEAT + kk * 32 + kb0);
      wr[ci][kk] = *(const frag8*)(Wr + (size_t)wrow * NFEAT + kk * 32 + kb0);
    }
  }

  for (int tile = blockIdx.x; tile < ntiles; tile += gridDim.x) {
    int m0 = tile * 16;
    int row = m0 + lr;
    bool rowok = row < M;
    frag8 aA[4], aX[4];
#pragma unroll
    for (int kk = 0; kk < 4; ++kk) {
      aA[kk] = frag8{};
      aX[kk] = frag8{};
      if (rowok) {
        aA[kk] = *(const frag8*)(A + (size_t)row * NFEAT + kk * 32 + kb0);
        if constexpr (X_IS_F32) {
          const float* xp = (const float*)X + (size_t)row * NFEAT + kk * 32 + kb0;
          float4 v0 = *(const float4*)xp;
          float4 v1 = *(const float4*)(xp + 4);
          frag8 a;
          a[0] = (short)f2bf(v0.x); a[1] = (short)f2bf(v0.y);
          a[2] = (short)f2bf(v0.z); a[3] = (short)f2bf(v0.w);
          a[4] = (short)f2bf(v1.x); a[5] = (short)f2bf(v1.y);
          a[6] = (short)f2bf(v1.z); a[7] = (short)f2bf(v1.w);
          aX[kk] = a;
        } else {
          aX[kk] = *(const frag8*)((const unsigned short*)X + (size_t)row * NFEAT + kk * 32 + kb0);
        }
      }
    }
    __syncthreads();  // all tile reads done before any in-place writes
    f32x4 acc[2] = {};
#pragma unroll
    for (int kk = 0; kk < 4; ++kk) {
#pragma unroll
      for (int ci = 0; ci < 2; ++ci) {
        acc[ci] = __builtin_amdgcn_mfma_f32_16x16x32_bf16(aA[kk], wl[ci][kk], acc[ci], 0, 0, 0);
        acc[ci] = __builtin_amdgcn_mfma_f32_16x16x32_bf16(aX[kk], wr[ci][kk], acc[ci], 0, 0, 0);
      }
    }
#pragma unroll
    for (int ci = 0; ci < 2; ++ci) {
#pragma unroll
      for (int r = 0; r < 4; ++r) {
        int orow = m0 + kq * 4 + r;
        if (orow < M) {
          int ocol = (wv * 2 + ci) * 16 + lr;
          float val = acc[ci][r] + bias_c[ci];
          Out[(size_t)orow * NFEAT + ocol] = f2bf(fmaxf(val, 0.f));
        }
      }
    }
  }
}

// ---------------- layer 3 (N_CLS=7) + log_softmax ----------------
__global__ void k_layer3(const unsigned int* __restrict__ A,
                         const unsigned int* __restrict__ H,
                         const float* __restrict__ W3l, const float* __restrict__ b3,
                         const float* __restrict__ W3r, float* __restrict__ out, int n) {
  int wv = threadIdx.x >> 6, lane = threadIdx.x & 63;
  int v = blockIdx.x * 4 + wv;
  if (v >= n) return;
  unsigned int ua = A[(size_t)v * (NFEAT / 2) + lane];
  unsigned int uh = H[(size_t)v * (NFEAT / 2) + lane];
  float a0 = bf2f((unsigned short)(ua & 0xffffu)), a1 = bf2f((unsigned short)(ua >> 16));
  float h0 = bf2f((unsigned short)(uh & 0xffffu)), h1 = bf2f((unsigned short)(uh >> 16));
  float s[7];
#pragma unroll
  for (int c = 0; c < 7; ++c) {
    float2 wl = *(const float2*)(W3l + c * NFEAT + lane * 2);
    float2 wr = *(const float2*)(W3r + c * NFEAT + lane * 2);
    s[c] = a0 * wl.x + a1 * wl.y + h0 * wr.x + h1 * wr.y;
  }
#pragma unroll
  for (int off = 32; off > 0; off >>= 1) {
#pragma unroll
    for (int c = 0; c < 7; ++c) s[c] += __shfl_xor(s[c], off);
  }
  float z[7], mx = -1e30f;
#pragma unroll
  for (int c = 0; c < 7; ++c) {
    z[c] = s[c] + b3[c];
    mx = fmaxf(mx, z[c]);
  }
  float se = 0.f;
#pragma unroll
  for (int c = 0; c < 7; ++c) se += __expf(z[c] - mx);
  float lse = mx + __logf(se);
  float val = z[0];
#pragma unroll
  for (int c = 1; c < 7; ++c) val = (lane == c) ? z[c] : val;
  if (lane < 7) out[(size_t)v * 7 + lane] = val - lse;
}

// ---------------- launch ----------------
extern "C" void kernel_launch(void* const* d_in, const int* in_sizes, int n_in,
                              void* d_out, int out_size, void* d_ws, size_t ws_size,
                              hipStream_t stream) {
  const float* x = (const float*)d_in[0];
  const int* ei = (const int*)d_in[1];
  const float* W1l = (const float*)d_in[2];
  const float* b1 = (const float*)d_in[3];
  const float* W1r = (const float*)d_in[4];
  const float* W2l = (const float*)d_in[5];
  const float* b2 = (const float*)d_in[6];
  const float* W2r = (const float*)d_in[7];
  const float* W3l = (const float*)d_in[8];
  const float* b3 = (const float*)d_in[9];
  const float* W3r = (const float*)d_in[10];
  float* out = (float*)d_out;

  int N = in_sizes[0] / NFEAT;
  int E = in_sizes[1] / 2;
  const int* src = ei;
  const int* dst = ei + E;

  char* ws = (char*)d_ws;
  size_t off = 0;
  auto alloc = [&](size_t bytes) {
    void* p = (void*)(ws + off);
    off += (bytes + 255) & ~(size_t)255;
    return p;
  };
  int* row_ptr = (int*)alloc((size_t)(N + 1) * 4);
  float* dinv = (float*)alloc((size_t)N * 4);
  int* bucket_cnt = (int*)alloc(512 * 4);
  int* bucket_base = (int*)alloc(513 * 4);
  int* bucket_cursor = (int*)alloc(512 * 4);
  int* csr = (int*)alloc((size_t)E * 4);
  unsigned short* Wbf = (unsigned short*)alloc((size_t)4 * 128 * 128 * 2);
  unsigned short* Abuf = (unsigned short*)alloc((size_t)N * NFEAT * 2);
  unsigned short* Bbuf = (unsigned short*)alloc((size_t)N * NFEAT * 2);
  size_t off_base = off;
  unsigned short* Xbf = (unsigned short*)alloc((size_t)N * NFEAT * 2);
  bool use_xbf = (off <= ws_size);
  if (!use_xbf) off = off_base;
  unsigned int* tmp = (unsigned int*)Abuf;  // aliased: tmp only live during CSR build

  int NB = (N + 255) >> 8;
  int chunk = (E + 255) / 256;

  hipMemsetAsync(bucket_cnt, 0, 512 * 4, stream);
  k_bucket_count<<<256, 256, 0, stream>>>(dst, bucket_cnt, E, NB, chunk);
  k_bucket_scan<<<1, 512, 0, stream>>>(bucket_cnt, bucket_base, bucket_cursor, NB, E);
  k_bucket_fill<<<256, 256, 0, stream>>>(src, dst, bucket_cursor, tmp, E, NB, chunk);
  k_local_sort<<<NB, 256, 0, stream>>>(tmp, bucket_base, csr, row_ptr, dinv, N, E);
  k_cvtw<<<(4 * 128 * 128) / 256, 256, 0, stream>>>(W1l, W1r, W2l, W2r, Wbf);
  if (use_xbf) {
    int npairs = N * (NFEAT / 2);
    k_cvtx<<<(npairs + 255) / 256, 256, 0, stream>>>(x, (unsigned int*)Xbf, npairs);
  }

  unsigned short* W1l_bf = Wbf;
  unsigned short* W1r_bf = Wbf + 16384;
  unsigned short* W2l_bf = Wbf + 32768;
  unsigned short* W2r_bf = Wbf + 49152;

  int gagg = (N + 3) / 4;
  int ntiles = (N + 15) / 16;
  int ggemm = min(ntiles, 1024);

  // layer 1
  if (use_xbf) {
    k_aggregate<false><<<gagg, 256, 0, stream>>>(Xbf, row_ptr, csr, dinv,
                                                 (unsigned int*)Abuf, N);
    k_gemm<false><<<ggemm, 256, 0, stream>>>(Abuf, Xbf, W1l_bf, W1r_bf, b1, Bbuf, N, ntiles);
  } else {
    k_aggregate<true><<<gagg, 256, 0, stream>>>(x, row_ptr, csr, dinv,
                                                (unsigned int*)Abuf, N);
    k_gemm<true><<<ggemm, 256, 0, stream>>>(Abuf, x, W1l_bf, W1r_bf, b1, Bbuf, N, ntiles);
  }
  // layer 2 (in-place over Bbuf; safe via intra-tile __syncthreads)
  k_aggregate<false><<<gagg, 256, 0, stream>>>(Bbuf, row_ptr, csr, dinv,
                                               (unsigned int*)Abuf, N);
  k_gemm<false><<<ggemm, 256, 0, stream>>>(Abuf, Bbuf, W2l_bf, W2r_bf, b2, Bbuf, N, ntiles);
  // layer 3
  k_aggregate<false><<<gagg, 256, 0, stream>>>(Bbuf, row_ptr, csr, dinv,
                                               (unsigned int*)Abuf, N);
  k_layer3<<<gagg, 256, 0, stream>>>((const unsigned int*)Abuf, (const unsigned int*)Bbuf,
                                     W3l, b3, W3r, out, N);
}